// Round 1
// baseline (1023.463 us; speedup 1.0000x reference)
//
#include <hip/hip_runtime.h>
#include <math.h>

#define NVIEWS 4
#define RESN 64
#define PP (RESN * RESN)        // 4096 rays per view
#define FEATC 32
#define PRES 256
#define NSAMP 92
#define NEAR_T 1.0f
#define FAR_T 2.7f
#define STEPF ((FAR_T - NEAR_T) / (float)NSAMP)
#define FOVF 0.8575560548920328f

#define RAYS_PER_BLOCK 4
#define TPB (RAYS_PER_BLOCK * 96)   // 384 threads, 6 waves

// -------- transpose planes (v,pl,c,y,x) -> (v,pl,y,x,c) --------
__global__ __launch_bounds__(PRES) void transpose_planes(
    const float* __restrict__ in, float* __restrict__ out) {
  int b  = blockIdx.x;          // vp*256 + y, vp in [0,12)
  int vp = b >> 8;
  int y  = b & 255;
  int x  = threadIdx.x;         // 0..255
  const float* src = in + (size_t)vp * FEATC * PRES * PRES + (size_t)y * PRES + x;
  float* dst = out + (((size_t)vp * PRES + y) * PRES + x) * FEATC;
  float v[FEATC];
#pragma unroll
  for (int c = 0; c < FEATC; ++c) v[c] = src[(size_t)c * PRES * PRES];
#pragma unroll
  for (int q = 0; q < FEATC / 4; ++q) {
    float4 t = make_float4(v[q * 4 + 0], v[q * 4 + 1], v[q * 4 + 2], v[q * 4 + 3]);
    *reinterpret_cast<float4*>(dst + q * 4) = t;
  }
}

// -------- fused render --------
template <int TR>
__global__ __launch_bounds__(TPB, 2) void render_kernel(
    const float* __restrict__ c2w,        // (4,4,4)
    const float* __restrict__ planes,     // TR: (4,3,256,256,32) else (4,3,32,256,256)
    const float* __restrict__ background, // (4,3)
    const float* __restrict__ t_jitter,   // (4,4096,92)
    const float* __restrict__ W1, const float* __restrict__ b1,   // (96,64),(64)
    const float* __restrict__ W2, const float* __restrict__ b2,   // (64,16),(16)
    const float* __restrict__ Wr1, const float* __restrict__ br1, // (18,64),(64)
    const float* __restrict__ Wr2, const float* __restrict__ br2, // (64,3),(3)
    float* __restrict__ out)              // (4,4096,3)
{
  __shared__ float lW1[96 * 64];
  __shared__ float lW2[64 * 16];
  __shared__ float lWr1[18 * 64];
  __shared__ float lWr2[64 * 3];
  __shared__ float lb1[64], lb2[16], lbr1[64], lbr2[3];
  __shared__ float4 comp[RAYS_PER_BLOCK][NSAMP];

  const int tid = threadIdx.x;
  for (int i = tid; i < 96 * 64; i += TPB) lW1[i] = W1[i];
  for (int i = tid; i < 64 * 16; i += TPB) lW2[i] = W2[i];
  for (int i = tid; i < 18 * 64; i += TPB) lWr1[i] = Wr1[i];
  for (int i = tid; i < 64 * 3;  i += TPB) lWr2[i] = Wr2[i];
  if (tid < 64) { lb1[tid] = b1[tid]; lbr1[tid] = br1[tid]; }
  if (tid < 16) lb2[tid] = b2[tid];
  if (tid < 3)  lbr2[tid] = br2[tid];
  __syncthreads();

  const int rl  = tid / 96;            // ray slot in block
  const int s   = tid % 96;            // sample index (active if < 92)
  const int ray = blockIdx.x * RAYS_PER_BLOCK + rl;
  const int view = ray >> 12;
  const int p    = ray & 4095;
  const int row  = p >> 6, col = p & 63;

  // camera
  const float foc = 0.5f * RESN / tanf(FOVF * 0.5f);
  const float dx = (col + 0.5f - RESN * 0.5f) / foc;
  const float dy = (row + 0.5f - RESN * 0.5f) / foc;
  const float* M = c2w + view * 16;
  const float rdx = M[0] * dx + M[1] * dy + M[2];
  const float rdy = M[4] * dx + M[5] * dy + M[6];
  const float rdz = M[8] * dx + M[9] * dy + M[10];
  const float rox = M[3] + 0.5f, roy = M[7] + 0.5f, roz = M[11] + 0.5f;

  if (s < NSAMP) {
    const float jit = t_jitter[((size_t)view * PP + p) * NSAMP + s];
    const float t = NEAR_T + ((float)s + jit) * STEPF + STEPF * 0.5f;
    const float px_ = fminf(fmaxf(rox + rdx * t, 0.f), 1.f);
    const float py_ = fminf(fmaxf(roy + rdy * t, 0.f), 1.f);
    const float pz_ = fminf(fmaxf(roz + rdz * t, 0.f), 1.f);

    float h[64];
#pragma unroll
    for (int j = 0; j < 64; ++j) h[j] = lb1[j];

    const float us[3] = {px_, px_, py_};
    const float vs[3] = {py_, pz_, pz_};
#pragma unroll
    for (int pl = 0; pl < 3; ++pl) {
      const float xf = us[pl] * 255.f;
      const float yf = vs[pl] * 255.f;
      const float x0f = floorf(xf), y0f = floorf(yf);
      const float wx = xf - x0f, wy = yf - y0f;
      const int x0 = (int)x0f, y0 = (int)y0f;
      const int x1 = min(x0 + 1, 255), y1 = min(y0 + 1, 255);
      const float w00 = (1.f - wx) * (1.f - wy), w01 = wx * (1.f - wy);
      const float w10 = (1.f - wx) * wy,         w11 = wx * wy;

      if (TR) {
        const size_t pb = (size_t)(view * 3 + pl) * PRES * PRES * FEATC;
        const float* p00 = planes + pb + ((size_t)y0 * PRES + x0) * FEATC;
        const float* p01 = planes + pb + ((size_t)y0 * PRES + x1) * FEATC;
        const float* p10 = planes + pb + ((size_t)y1 * PRES + x0) * FEATC;
        const float* p11 = planes + pb + ((size_t)y1 * PRES + x1) * FEATC;
#pragma unroll
        for (int c4 = 0; c4 < 8; ++c4) {
          const float4 a = *reinterpret_cast<const float4*>(p00 + c4 * 4);
          const float4 b = *reinterpret_cast<const float4*>(p01 + c4 * 4);
          const float4 c = *reinterpret_cast<const float4*>(p10 + c4 * 4);
          const float4 d = *reinterpret_cast<const float4*>(p11 + c4 * 4);
          const float f0 = a.x * w00 + b.x * w01 + c.x * w10 + d.x * w11;
          const float f1 = a.y * w00 + b.y * w01 + c.y * w10 + d.y * w11;
          const float f2 = a.z * w00 + b.z * w01 + c.z * w10 + d.z * w11;
          const float f3 = a.w * w00 + b.w * w01 + c.w * w10 + d.w * w11;
          const float4* wr0 = reinterpret_cast<const float4*>(&lW1[(pl * 32 + c4 * 4 + 0) * 64]);
          const float4* wr1 = reinterpret_cast<const float4*>(&lW1[(pl * 32 + c4 * 4 + 1) * 64]);
          const float4* wr2 = reinterpret_cast<const float4*>(&lW1[(pl * 32 + c4 * 4 + 2) * 64]);
          const float4* wr3 = reinterpret_cast<const float4*>(&lW1[(pl * 32 + c4 * 4 + 3) * 64]);
#pragma unroll
          for (int j4 = 0; j4 < 16; ++j4) {
            const float4 w0 = wr0[j4], w1 = wr1[j4], w2 = wr2[j4], w3 = wr3[j4];
            h[j4 * 4 + 0] += f0 * w0.x + f1 * w1.x + f2 * w2.x + f3 * w3.x;
            h[j4 * 4 + 1] += f0 * w0.y + f1 * w1.y + f2 * w2.y + f3 * w3.y;
            h[j4 * 4 + 2] += f0 * w0.z + f1 * w1.z + f2 * w2.z + f3 * w3.z;
            h[j4 * 4 + 3] += f0 * w0.w + f1 * w1.w + f2 * w2.w + f3 * w3.w;
          }
        }
      } else {
        const float* bp = planes + (size_t)(view * 3 + pl) * FEATC * PRES * PRES;
        const int o00 = y0 * PRES + x0, o01 = y0 * PRES + x1;
        const int o10 = y1 * PRES + x0, o11 = y1 * PRES + x1;
#pragma unroll 4
        for (int c = 0; c < 32; ++c) {
          const float* pc = bp + (size_t)c * PRES * PRES;
          const float f = pc[o00] * w00 + pc[o01] * w01 + pc[o10] * w10 + pc[o11] * w11;
          const float4* wr = reinterpret_cast<const float4*>(&lW1[(pl * 32 + c) * 64]);
#pragma unroll
          for (int j4 = 0; j4 < 16; ++j4) {
            const float4 w = wr[j4];
            h[j4 * 4 + 0] += f * w.x;
            h[j4 * 4 + 1] += f * w.y;
            h[j4 * 4 + 2] += f * w.z;
            h[j4 * 4 + 3] += f * w.w;
          }
        }
      }
    }

    // relu + layer 2: o = h @ W2 + b2
    float o[16];
#pragma unroll
    for (int k = 0; k < 16; ++k) o[k] = lb2[k];
#pragma unroll
    for (int j = 0; j < 64; ++j) {
      const float hj = fmaxf(h[j], 0.f);
      const float4* wr = reinterpret_cast<const float4*>(&lW2[j * 16]);
#pragma unroll
      for (int k4 = 0; k4 < 4; ++k4) {
        const float4 w = wr[k4];
        o[k4 * 4 + 0] += hj * w.x;
        o[k4 * 4 + 1] += hj * w.y;
        o[k4 * 4 + 2] += hj * w.z;
        o[k4 * 4 + 3] += hj * w.w;
      }
    }

    // sigma -> alpha
    const float so = o[0];
    const float sigma = fmaxf(so, 0.f) + log1pf(expf(-fabsf(so)));
    const float alpha = 1.f - expf(-sigma * STEPF);

    // color head: hr = relu([dir, geo] @ Wr1 + br1); rgb = sigmoid(hr @ Wr2 + br2)
    float r0 = lbr2[0], r1 = lbr2[1], r2 = lbr2[2];
#pragma unroll
    for (int j4 = 0; j4 < 16; ++j4) {
      const float4 bb = reinterpret_cast<const float4*>(lbr1)[j4];
      const float4 wd0 = reinterpret_cast<const float4*>(&lWr1[0 * 64])[j4];
      const float4 wd1 = reinterpret_cast<const float4*>(&lWr1[1 * 64])[j4];
      const float4 wd2 = reinterpret_cast<const float4*>(&lWr1[2 * 64])[j4];
      float a0 = bb.x + rdx * wd0.x + rdy * wd1.x + rdz * wd2.x;
      float a1 = bb.y + rdx * wd0.y + rdy * wd1.y + rdz * wd2.y;
      float a2 = bb.z + rdx * wd0.z + rdy * wd1.z + rdz * wd2.z;
      float a3 = bb.w + rdx * wd0.w + rdy * wd1.w + rdz * wd2.w;
#pragma unroll
      for (int i = 0; i < 15; ++i) {
        const float g = o[i + 1];
        const float4 w = reinterpret_cast<const float4*>(&lWr1[(3 + i) * 64])[j4];
        a0 += g * w.x; a1 += g * w.y; a2 += g * w.z; a3 += g * w.w;
      }
      a0 = fmaxf(a0, 0.f); a1 = fmaxf(a1, 0.f); a2 = fmaxf(a2, 0.f); a3 = fmaxf(a3, 0.f);
      const int j = j4 * 4;
      r0 += a0 * lWr2[(j + 0) * 3 + 0] + a1 * lWr2[(j + 1) * 3 + 0] +
            a2 * lWr2[(j + 2) * 3 + 0] + a3 * lWr2[(j + 3) * 3 + 0];
      r1 += a0 * lWr2[(j + 0) * 3 + 1] + a1 * lWr2[(j + 1) * 3 + 1] +
            a2 * lWr2[(j + 2) * 3 + 1] + a3 * lWr2[(j + 3) * 3 + 1];
      r2 += a0 * lWr2[(j + 0) * 3 + 2] + a1 * lWr2[(j + 1) * 3 + 2] +
            a2 * lWr2[(j + 2) * 3 + 2] + a3 * lWr2[(j + 3) * 3 + 2];
    }
    r0 = 1.f / (1.f + expf(-r0));
    r1 = 1.f / (1.f + expf(-r1));
    r2 = 1.f / (1.f + expf(-r2));

    comp[rl][s] = make_float4(alpha, r0, r1, r2);
  }

  __syncthreads();

  if (s == 0) {
    float T = 1.f, accA = 0.f, cr = 0.f, cg = 0.f, cb = 0.f;
    for (int i = 0; i < NSAMP; ++i) {
      const float4 cv = comp[rl][i];
      const float a = cv.x;
      const float w = T * a;
      cr += w * cv.y; cg += w * cv.z; cb += w * cv.w;
      accA += w;
      T *= (1.f - a + 1e-10f);
    }
    const float* bg = background + view * 3;
    float* po = out + (size_t)ray * 3;
    po[0] = cr + (1.f - accA) * bg[0];
    po[1] = cg + (1.f - accA) * bg[1];
    po[2] = cb + (1.f - accA) * bg[2];
  }
}

extern "C" void kernel_launch(void* const* d_in, const int* in_sizes, int n_in,
                              void* d_out, int out_size, void* d_ws, size_t ws_size,
                              hipStream_t stream) {
  const float* c2w        = (const float*)d_in[0];
  const float* planes     = (const float*)d_in[1];
  const float* background = (const float*)d_in[2];
  const float* t_jitter   = (const float*)d_in[3];
  const float* W1  = (const float*)d_in[4];
  const float* b1  = (const float*)d_in[5];
  const float* W2  = (const float*)d_in[6];
  const float* b2  = (const float*)d_in[7];
  const float* Wr1 = (const float*)d_in[8];
  const float* br1 = (const float*)d_in[9];
  const float* Wr2 = (const float*)d_in[10];
  const float* br2 = (const float*)d_in[11];
  float* out = (float*)d_out;

  const int n_blocks = NVIEWS * PP / RAYS_PER_BLOCK;  // 4096
  const size_t tr_bytes = (size_t)NVIEWS * 3 * PRES * PRES * FEATC * sizeof(float);

  if (ws_size >= tr_bytes) {
    float* tp = (float*)d_ws;
    transpose_planes<<<NVIEWS * 3 * PRES, PRES, 0, stream>>>(planes, tp);
    render_kernel<1><<<n_blocks, TPB, 0, stream>>>(
        c2w, tp, background, t_jitter, W1, b1, W2, b2, Wr1, br1, Wr2, br2, out);
  } else {
    render_kernel<0><<<n_blocks, TPB, 0, stream>>>(
        c2w, planes, background, t_jitter, W1, b1, W2, b2, Wr1, br1, Wr2, br2, out);
  }
}

// Round 2
// 381.379 us; speedup vs baseline: 2.6836x; 2.6836x over previous
//
#include <hip/hip_runtime.h>
#include <math.h>

typedef __bf16 bf16x8 __attribute__((ext_vector_type(8)));
typedef float f32x4 __attribute__((ext_vector_type(4)));

#define NVIEWS 4
#define RESN 64
#define PP 4096
#define FEATC 32
#define PRES 256
#define NSAMP 92
#define STEPF ((2.7f - 1.0f) / 92.0f)
#define FOVF 0.8575560548920328f

#define RPB 8                 // rays per block
#define SB (RPB * NSAMP)      // 736 samples per block
#define TPB 512               // 8 waves
#define CH 256                // samples per chunk
#define NCHUNK 3
#define HPAD 72               // hbuf row stride (bf16 elems), 144B = mult of 16
#define CPAD 40               // cA row stride, 80B = mult of 16

// -------- transpose planes (v,pl,c,y,x) -> (v,pl,y,x,c) --------
__global__ __launch_bounds__(PRES) void transpose_planes(
    const float* __restrict__ in, float* __restrict__ out) {
  int b  = blockIdx.x;          // vp*256 + y
  int vp = b >> 8;
  int y  = b & 255;
  int x  = threadIdx.x;
  const float* src = in + (size_t)vp * FEATC * PRES * PRES + (size_t)y * PRES + x;
  float* dst = out + (((size_t)vp * PRES + y) * PRES + x) * FEATC;
  float v[FEATC];
#pragma unroll
  for (int c = 0; c < FEATC; ++c) v[c] = src[(size_t)c * PRES * PRES];
#pragma unroll
  for (int q = 0; q < FEATC / 4; ++q) {
    float4 t = make_float4(v[q * 4 + 0], v[q * 4 + 1], v[q * 4 + 2], v[q * 4 + 3]);
    *reinterpret_cast<float4*>(dst + q * 4) = t;
  }
}

__device__ __forceinline__ unsigned short f2bf(float x) {
  unsigned int u = __float_as_uint(x);
  u += 0x7fffu + ((u >> 16) & 1u);
  return (unsigned short)(u >> 16);
}

// -------- fused MFMA render --------
template <int TR>
__global__ __launch_bounds__(TPB, 2) void render_mfma(
    const float* __restrict__ c2w, const float* __restrict__ planes,
    const float* __restrict__ background, const float* __restrict__ t_jitter,
    const float* __restrict__ W1, const float* __restrict__ b1,
    const float* __restrict__ W2, const float* __restrict__ b2,
    const float* __restrict__ Wr1, const float* __restrict__ br1,
    const float* __restrict__ Wr2, const float* __restrict__ br2,
    float* __restrict__ out) {
  __shared__ __bf16 hbuf[CH][HPAD];          // feat (cols 0-31) -> h (0-63) -> hr (0-63)
  __shared__ __bf16 cA[CH][CPAD];            // color-head A: dir(0-2), geo(3-17), 0(18-31)
  __shared__ unsigned char ureg[7360] __attribute__((aligned(16)));  // wstage | alpha+rgb
  __shared__ float b1L[64], b2L[16], br1L[64], br2L[4];

  unsigned short* wstage = (unsigned short*)ureg;
  float* alphaL = (float*)ureg;              // [736] f32
  __bf16* rgbL = (__bf16*)(ureg + 2944);     // [736*3] bf16

  const int tid = threadIdx.x;
  const int w = tid >> 6;        // wave 0..7
  const int lane = tid & 63;
  const int lr = lane & 15;
  const int lg = lane >> 4;      // 0..3

  // zero cA cols 16..31 once (cols 16,17 rewritten by geo each chunk)
  {
    uint4 z = make_uint4(0, 0, 0, 0);
    *(uint4*)((unsigned int*)&cA[tid >> 1][16] + (tid & 1) * 4) = z;
  }

  // ---------------- weight preload into per-lane B-fragments ----------------
  bf16x8 fW1[3][4], fW2[2], fR1[4], fR2[2];
#pragma unroll
  for (int ks = 0; ks < 3; ++ks) {           // W1: 3 K-parts of 32 rows
    if (ks) __syncthreads();
    {
      const float4 g = *(const float4*)&W1[ks * 2048 + tid * 4];
      unsigned int lo = (unsigned int)f2bf(g.x) | ((unsigned int)f2bf(g.y) << 16);
      unsigned int hi = (unsigned int)f2bf(g.z) | ((unsigned int)f2bf(g.w) << 16);
      *(uint2*)&wstage[tid * 4] = make_uint2(lo, hi);
    }
    __syncthreads();
#pragma unroll
    for (int nt = 0; nt < 4; ++nt) {
      union { unsigned short u[8]; bf16x8 b; } t;
#pragma unroll
      for (int i = 0; i < 8; ++i) t.u[i] = wstage[(lg * 8 + i) * 64 + nt * 16 + lr];
      fW1[ks][nt] = t.b;
    }
  }
  __syncthreads();
  if (tid < 256) {                            // W2: 64x16
    const float4 g = *(const float4*)&W2[tid * 4];
    unsigned int lo = (unsigned int)f2bf(g.x) | ((unsigned int)f2bf(g.y) << 16);
    unsigned int hi = (unsigned int)f2bf(g.z) | ((unsigned int)f2bf(g.w) << 16);
    *(uint2*)&wstage[tid * 4] = make_uint2(lo, hi);
  }
  __syncthreads();
#pragma unroll
  for (int ks = 0; ks < 2; ++ks) {
    union { unsigned short u[8]; bf16x8 b; } t;
#pragma unroll
    for (int i = 0; i < 8; ++i) t.u[i] = wstage[(ks * 32 + lg * 8 + i) * 16 + lr];
    fW2[ks] = t.b;
  }
  __syncthreads();
  if (tid < 288) {                            // Wr1: 18x64 (K-pad to 32 with zeros)
    const float4 g = *(const float4*)&Wr1[tid * 4];
    unsigned int lo = (unsigned int)f2bf(g.x) | ((unsigned int)f2bf(g.y) << 16);
    unsigned int hi = (unsigned int)f2bf(g.z) | ((unsigned int)f2bf(g.w) << 16);
    *(uint2*)&wstage[tid * 4] = make_uint2(lo, hi);
  }
  __syncthreads();
#pragma unroll
  for (int nt = 0; nt < 4; ++nt) {
    union { unsigned short u[8]; bf16x8 b; } t;
#pragma unroll
    for (int i = 0; i < 8; ++i) {
      const int k = lg * 8 + i;
      t.u[i] = (k < 18) ? wstage[k * 64 + nt * 16 + lr] : (unsigned short)0;
    }
    fR1[nt] = t.b;
  }
  __syncthreads();
  if (tid < 48) {                             // Wr2: 64x3 (N-pad to 16)
    const float4 g = *(const float4*)&Wr2[tid * 4];
    unsigned int lo = (unsigned int)f2bf(g.x) | ((unsigned int)f2bf(g.y) << 16);
    unsigned int hi = (unsigned int)f2bf(g.z) | ((unsigned int)f2bf(g.w) << 16);
    *(uint2*)&wstage[tid * 4] = make_uint2(lo, hi);
  }
  if (tid < 64) { b1L[tid] = b1[tid]; br1L[tid] = br1[tid]; }
  if (tid < 16) b2L[tid] = b2[tid];
  if (tid < 4)  br2L[tid] = (tid < 3) ? br2[tid] : 0.f;
  __syncthreads();
#pragma unroll
  for (int ks = 0; ks < 2; ++ks) {
    union { unsigned short u[8]; bf16x8 b; } t;
#pragma unroll
    for (int i = 0; i < 8; ++i)
      t.u[i] = (lr < 3) ? wstage[(ks * 32 + lg * 8 + i) * 3 + lr] : (unsigned short)0;
    fR2[ks] = t.b;
  }
  __syncthreads();   // wstage dead; ureg becomes alpha/rgb

  const float foc = 0.5f * (float)RESN / tanf(FOVF * 0.5f);

  for (int chunk = 0; chunk < NCHUNK; ++chunk) {
    // ---- chunk setup: 2 threads per sample compute pos/dir ----
    const int mc = tid >> 1;
    const int half = tid & 1;
    const int sb = chunk * CH + mc;
    const bool valid = sb < SB;
    float px = 0, py = 0, pz = 0;
    int view = 0;
    if (valid) {
      const int rb = sb / NSAMP;
      const int s = sb - rb * NSAMP;
      const int ray = blockIdx.x * RPB + rb;
      view = ray >> 12;
      const int p = ray & 4095;
      const float dx = ((float)(p & 63) + 0.5f - 32.f) / foc;
      const float dy = ((float)(p >> 6) + 0.5f - 32.f) / foc;
      const float* M = c2w + view * 16;
      const float rdx = M[0] * dx + M[1] * dy + M[2];
      const float rdy = M[4] * dx + M[5] * dy + M[6];
      const float rdz = M[8] * dx + M[9] * dy + M[10];
      const float jit = t_jitter[(size_t)ray * NSAMP + s];
      const float t = 1.0f + ((float)s + jit) * STEPF + STEPF * 0.5f;
      px = fminf(fmaxf(M[3] + 0.5f + rdx * t, 0.f), 1.f);
      py = fminf(fmaxf(M[7] + 0.5f + rdy * t, 0.f), 1.f);
      pz = fminf(fmaxf(M[11] + 0.5f + rdz * t, 0.f), 1.f);
      if (half == 0) {
        cA[mc][0] = (__bf16)rdx; cA[mc][1] = (__bf16)rdy; cA[mc][2] = (__bf16)rdz;
      }
    }

    // ---- GEMM1: feat[256x96] @ W1[96x64], K streamed per plane ----
    f32x4 acc1[2][4] = {};
#pragma unroll
    for (int pl = 0; pl < 3; ++pl) {
      __syncthreads();                       // hbuf free (prev reads done)
      if (valid) {
        const float uu = (pl == 2) ? py : px;
        const float vv = (pl == 0) ? py : pz;
        const float xf = uu * 255.f, yf = vv * 255.f;
        const float x0f = floorf(xf), y0f = floorf(yf);
        const float wx = xf - x0f, wy = yf - y0f;
        const int x0 = (int)x0f, y0 = (int)y0f;
        const int x1 = min(x0 + 1, 255), y1 = min(y0 + 1, 255);
        const float w00 = (1.f - wx) * (1.f - wy), w01 = wx * (1.f - wy);
        const float w10 = (1.f - wx) * wy, w11 = wx * wy;
        float f[16];
        if (TR) {
          const float* pb = planes + (size_t)(view * 3 + pl) * (PRES * PRES * FEATC) + half * 16;
          const float* p00 = pb + (size_t)(y0 * 256 + x0) * 32;
          const float* p01 = pb + (size_t)(y0 * 256 + x1) * 32;
          const float* p10 = pb + (size_t)(y1 * 256 + x0) * 32;
          const float* p11 = pb + (size_t)(y1 * 256 + x1) * 32;
#pragma unroll
          for (int q = 0; q < 4; ++q) {
            const float4 a = *(const float4*)(p00 + q * 4);
            const float4 b = *(const float4*)(p01 + q * 4);
            const float4 c = *(const float4*)(p10 + q * 4);
            const float4 d = *(const float4*)(p11 + q * 4);
            f[q * 4 + 0] = a.x * w00 + b.x * w01 + c.x * w10 + d.x * w11;
            f[q * 4 + 1] = a.y * w00 + b.y * w01 + c.y * w10 + d.y * w11;
            f[q * 4 + 2] = a.z * w00 + b.z * w01 + c.z * w10 + d.z * w11;
            f[q * 4 + 3] = a.w * w00 + b.w * w01 + c.w * w10 + d.w * w11;
          }
        } else {
          const float* pb = planes + (size_t)(view * 3 + pl) * (FEATC * PRES * PRES) +
                            (size_t)(half * 16) * (PRES * PRES);
          const int o00 = y0 * 256 + x0, o01 = y0 * 256 + x1;
          const int o10 = y1 * 256 + x0, o11 = y1 * 256 + x1;
#pragma unroll
          for (int cc = 0; cc < 16; ++cc) {
            const float* pc = pb + (size_t)cc * (PRES * PRES);
            f[cc] = pc[o00] * w00 + pc[o01] * w01 + pc[o10] * w10 + pc[o11] * w11;
          }
        }
        bf16x8 v0, v1;
#pragma unroll
        for (int i = 0; i < 8; ++i) { v0[i] = (__bf16)f[i]; v1[i] = (__bf16)f[8 + i]; }
        *(bf16x8*)&hbuf[mc][half * 16] = v0;
        *(bf16x8*)&hbuf[mc][half * 16 + 8] = v1;
      }
      __syncthreads();
#pragma unroll
      for (int mt = 0; mt < 2; ++mt) {
        const int m = (2 * w + mt) * 16 + lr;
        const bf16x8 a = *(const bf16x8*)&hbuf[m][lg * 8];
#pragma unroll
        for (int nt = 0; nt < 4; ++nt)
          acc1[mt][nt] = __builtin_amdgcn_mfma_f32_16x16x32_bf16(a, fW1[pl][nt], acc1[mt][nt], 0, 0, 0);
      }
    }
    __syncthreads();
    // h = relu(acc + b1) -> hbuf cols 0..63 (bf16)
#pragma unroll
    for (int mt = 0; mt < 2; ++mt)
#pragma unroll
      for (int nt = 0; nt < 4; ++nt)
#pragma unroll
        for (int r = 0; r < 4; ++r) {
          const int m = (2 * w + mt) * 16 + lg * 4 + r;
          const int n = nt * 16 + lr;
          hbuf[m][n] = (__bf16)fmaxf(acc1[mt][nt][r] + b1L[n], 0.f);
        }
    __syncthreads();
    // ---- GEMM2: h[256x64] @ W2[64x16] ----
    f32x4 acc2[2] = {};
#pragma unroll
    for (int mt = 0; mt < 2; ++mt) {
      const int m = (2 * w + mt) * 16 + lr;
      const bf16x8 a0 = *(const bf16x8*)&hbuf[m][lg * 8];
      const bf16x8 a1 = *(const bf16x8*)&hbuf[m][32 + lg * 8];
      acc2[mt] = __builtin_amdgcn_mfma_f32_16x16x32_bf16(a0, fW2[0], acc2[mt], 0, 0, 0);
      acc2[mt] = __builtin_amdgcn_mfma_f32_16x16x32_bf16(a1, fW2[1], acc2[mt], 0, 0, 0);
    }
#pragma unroll
    for (int mt = 0; mt < 2; ++mt)
#pragma unroll
      for (int r = 0; r < 4; ++r) {
        const int m = (2 * w + mt) * 16 + lg * 4 + r;
        const int sb2 = chunk * CH + m;
        const float val = acc2[mt][r] + b2L[lr];
        if (lr == 0) {
          const float sp = fmaxf(val, 0.f) + log1pf(expf(-fabsf(val)));
          const float alpha = 1.f - expf(-sp * STEPF);
          if (sb2 < SB) alphaL[sb2] = alpha;
        } else {
          cA[m][2 + lr] = (__bf16)val;   // geo i = lr-1 -> col 3+(lr-1)
        }
      }
    __syncthreads();
    // ---- GEMM3: [dir,geo,0][256x32] @ Wr1p[32x64] ----
    f32x4 acc3[2][4] = {};
#pragma unroll
    for (int mt = 0; mt < 2; ++mt) {
      const int m = (2 * w + mt) * 16 + lr;
      const bf16x8 a = *(const bf16x8*)&cA[m][lg * 8];
#pragma unroll
      for (int nt = 0; nt < 4; ++nt)
        acc3[mt][nt] = __builtin_amdgcn_mfma_f32_16x16x32_bf16(a, fR1[nt], acc3[mt][nt], 0, 0, 0);
    }
    // hr = relu(acc + br1) -> hbuf (safe: all GEMM2 reads completed at last barrier)
#pragma unroll
    for (int mt = 0; mt < 2; ++mt)
#pragma unroll
      for (int nt = 0; nt < 4; ++nt)
#pragma unroll
        for (int r = 0; r < 4; ++r) {
          const int m = (2 * w + mt) * 16 + lg * 4 + r;
          const int n = nt * 16 + lr;
          hbuf[m][n] = (__bf16)fmaxf(acc3[mt][nt][r] + br1L[n], 0.f);
        }
    __syncthreads();
    // ---- GEMM4: hr[256x64] @ Wr2p[64x16] ----
    f32x4 acc4[2] = {};
#pragma unroll
    for (int mt = 0; mt < 2; ++mt) {
      const int m = (2 * w + mt) * 16 + lr;
      const bf16x8 a0 = *(const bf16x8*)&hbuf[m][lg * 8];
      const bf16x8 a1 = *(const bf16x8*)&hbuf[m][32 + lg * 8];
      acc4[mt] = __builtin_amdgcn_mfma_f32_16x16x32_bf16(a0, fR2[0], acc4[mt], 0, 0, 0);
      acc4[mt] = __builtin_amdgcn_mfma_f32_16x16x32_bf16(a1, fR2[1], acc4[mt], 0, 0, 0);
    }
#pragma unroll
    for (int mt = 0; mt < 2; ++mt)
#pragma unroll
      for (int r = 0; r < 4; ++r) {
        const int m = (2 * w + mt) * 16 + lg * 4 + r;
        const int sb2 = chunk * CH + m;
        if (lr < 3 && sb2 < SB) {
          const float v = acc4[mt][r] + br2L[lr];
          rgbL[sb2 * 3 + lr] = (__bf16)(1.f / (1.f + expf(-v)));
        }
      }
    __syncthreads();   // protect hbuf/cA for next chunk
  }

  // ---- composite: one thread per ray ----
  if (tid < RPB) {
    const int ray = blockIdx.x * RPB + tid;
    const int view2 = ray >> 12;
    float T = 1.f, accA = 0.f, cr = 0.f, cg = 0.f, cb = 0.f;
    for (int i = 0; i < NSAMP; ++i) {
      const int idx = tid * NSAMP + i;
      const float a = alphaL[idx];
      const float wgt = T * a;
      cr += wgt * (float)rgbL[idx * 3 + 0];
      cg += wgt * (float)rgbL[idx * 3 + 1];
      cb += wgt * (float)rgbL[idx * 3 + 2];
      accA += wgt;
      T *= (1.f - a + 1e-10f);
    }
    const float* bg = background + view2 * 3;
    float* po = out + (size_t)ray * 3;
    po[0] = cr + (1.f - accA) * bg[0];
    po[1] = cg + (1.f - accA) * bg[1];
    po[2] = cb + (1.f - accA) * bg[2];
  }
}

extern "C" void kernel_launch(void* const* d_in, const int* in_sizes, int n_in,
                              void* d_out, int out_size, void* d_ws, size_t ws_size,
                              hipStream_t stream) {
  const float* c2w        = (const float*)d_in[0];
  const float* planes     = (const float*)d_in[1];
  const float* background = (const float*)d_in[2];
  const float* t_jitter   = (const float*)d_in[3];
  const float* W1  = (const float*)d_in[4];
  const float* b1  = (const float*)d_in[5];
  const float* W2  = (const float*)d_in[6];
  const float* b2  = (const float*)d_in[7];
  const float* Wr1 = (const float*)d_in[8];
  const float* br1 = (const float*)d_in[9];
  const float* Wr2 = (const float*)d_in[10];
  const float* br2 = (const float*)d_in[11];
  float* out = (float*)d_out;

  const int n_blocks = NVIEWS * PP / RPB;  // 2048
  const size_t tr_bytes = (size_t)NVIEWS * 3 * PRES * PRES * FEATC * sizeof(float);

  if (ws_size >= tr_bytes) {
    float* tp = (float*)d_ws;
    transpose_planes<<<NVIEWS * 3 * PRES, PRES, 0, stream>>>(planes, tp);
    render_mfma<1><<<n_blocks, TPB, 0, stream>>>(
        c2w, tp, background, t_jitter, W1, b1, W2, b2, Wr1, br1, Wr2, br2, out);
  } else {
    render_mfma<0><<<n_blocks, TPB, 0, stream>>>(
        c2w, planes, background, t_jitter, W1, b1, W2, b2, Wr1, br1, Wr2, br2, out);
  }
}